// Round 7
// baseline (161.363 us; speedup 1.0000x reference)
//
#include <hip/hip_runtime.h>

// B=16, C=256, HEADS=4, d=64, N=W*H=1024
constexpr int Bb  = 16;
constexpr int Cch = 256;
constexpr int NH  = 4;
constexpr int Dh  = 64;
constexpr int Nn  = 1024;

typedef _Float16 f16;
typedef __attribute__((ext_vector_type(8))) _Float16 f16x8;
typedef __attribute__((ext_vector_type(4))) _Float16 f16x4;
typedef __attribute__((ext_vector_type(4))) float    f32x4;

#define LOG2E 1.44269504088896f

// async 16B global->LDS. lds base must be wave-uniform; HW adds lane*16.
__device__ inline void gld16(const f16* g, const f16* lds_wave_base) {
    __builtin_amdgcn_global_load_lds(
        (const __attribute__((address_space(1))) unsigned int*)g,
        (__attribute__((address_space(3))) unsigned int*)lds_wave_base,
        16, 0, 0);
}

// ---------------------------------------------------------------------------
// Fused prep: xtrans (blocks 0..1023) | relt (1024..2047) | wcast (2048..2815)
// rel is pre-scaled by log2e (softmax via exp2).
// ---------------------------------------------------------------------------
__global__ __launch_bounds__(256) void prep_kernel(
    const float* __restrict__ x,
    const float* __restrict__ Wq, const float* __restrict__ Wk,
    const float* __restrict__ Wv,
    const float* __restrict__ rel_h, const float* __restrict__ rel_w,
    f16* __restrict__ xt, f16* __restrict__ Wh, f16* __restrict__ rel_t)
{
    const int gx = blockIdx.x;
    const int t  = threadIdx.x;
    __shared__ float T[64][65];

    if (gx < 1024) {
        const int n0 = (gx & 15) * 64;
        const int c0 = ((gx >> 4) & 3) * 64;
        const int b  = gx >> 6;
        #pragma unroll
        for (int rep = 0; rep < 16; rep++) {
            const int e  = t + rep * 256;
            const int r  = e >> 6;
            const int cc = e & 63;
            T[r][cc] = x[((size_t)b * Cch + c0 + r) * Nn + n0 + cc];
        }
        __syncthreads();
        #pragma unroll
        for (int rep = 0; rep < 4; rep++) {
            const int e  = t + rep * 256;
            const int nn = e >> 4;
            const int c4 = e & 15;
            f16x4 w;
            w.x = (f16)T[c4 * 4 + 0][nn];
            w.y = (f16)T[c4 * 4 + 1][nn];
            w.z = (f16)T[c4 * 4 + 2][nn];
            w.w = (f16)T[c4 * 4 + 3][nn];
            *(f16x4*)&xt[((size_t)b * Nn + n0 + nn) * Cch + c0 + c4 * 4] = w;
        }
    } else if (gx < 2048) {
        const int idx = (gx - 1024) * 256 + t;     // NH*Nn*Dh = 262144
        const int d = idx & 63;
        const int n = (idx >> 6) & (Nn - 1);
        const int h = idx >> 16;
        const int hd = h * 64 + d;
        rel_t[idx] = (f16)((rel_h[hd * 32 + (n & 31)] + rel_w[hd * 32 + (n >> 5)])
                           * LOG2E);
    } else {
        const int idx = (gx - 2048) * 256 + t;     // 768*256
        const int og  = idx >> 8;
        const int c   = idx & 255;
        const int p   = og >> 8;
        const int o   = og & 255;
        const float* W = (p == 0) ? Wq : (p == 1) ? Wk : Wv;
        Wh[idx] = (f16)W[o * 256 + c];
    }
}

// ---------------------------------------------------------------------------
// QKV projection GEMM, fp16 MFMA, BK=64, global_load_lds + source-XOR swizzle.
// k output pre-scaled by log2e.
// grid = (8 n-tiles, 6 o-tiles over 768, B); block = 256 (4 waves, 2x2)
// ---------------------------------------------------------------------------
__global__ __launch_bounds__(256, 3) void gemm_qkv(
    const f16* __restrict__ Wh, const f16* __restrict__ xt,
    const float* __restrict__ bq, const float* __restrict__ bk,
    const float* __restrict__ bv,
    f16* __restrict__ qt, f16* __restrict__ kt, f16* __restrict__ vb)
{
    const int bx   = blockIdx.x;
    const int y    = blockIdx.y;
    const int b    = blockIdx.z;
    const int p    = y >> 1;
    const int half = y & 1;

    // rows of 64 f16 (128 B), XOR-swizzled chunks (8 per row), no pad
    __shared__ f16 Wt[128 * 64];   // 16 KB
    __shared__ f16 Xt[128 * 64];   // 16 KB

    const int t    = threadIdx.x;
    const int wave = t >> 6;
    const int lane = t & 63;
    const int l16  = lane & 15;
    const int quad = lane >> 4;
    const int wm   = wave >> 1;
    const int wsd  = wave & 1;

    f32x4 acc[4][4];
    #pragma unroll
    for (int mi = 0; mi < 4; mi++)
        #pragma unroll
        for (int ni = 0; ni < 4; ni++) acc[mi][ni] = (f32x4){0.f, 0.f, 0.f, 0.f};

    const f16* Wg = Wh + (size_t)y * 128 * 256;
    const f16* Xg = xt + ((size_t)b * Nn + bx * 128) * 256;

    for (int c0 = 0; c0 < 256; c0 += 64) {
        __syncthreads();   // prior iter's fragment reads done
        #pragma unroll
        for (int rep = 0; rep < 4; rep++) {
            const int e   = t + rep * 256;       // 1024 chunks: 128 rows x 8
            const int row = e >> 3;
            const int c8s = (e & 7) ^ (row & 7);
            gld16(&Wg[(size_t)row * 256 + c0 + c8s * 8],
                  &Wt[((size_t)rep * 256 + wave * 64) * 8]);
        }
        #pragma unroll
        for (int rep = 0; rep < 4; rep++) {
            const int e   = t + rep * 256;
            const int row = e >> 3;
            const int c8s = (e & 7) ^ (row & 7);
            gld16(&Xg[(size_t)row * 256 + c0 + c8s * 8],
                  &Xt[((size_t)rep * 256 + wave * 64) * 8]);
        }
        __syncthreads();   // drains vmcnt -> LDS ready

        const f16* tf = (p < 2) ? Wt : Xt;
        const f16* ts = (p < 2) ? Xt : Wt;
        #pragma unroll
        for (int kk = 0; kk < 2; kk++) {
            f16x8 af[4], bf[4];
            #pragma unroll
            for (int mi = 0; mi < 4; mi++) {
                const int row = wm * 64 + mi * 16 + l16;
                af[mi] = *(const f16x8*)
                    &tf[row * 64 + (((kk * 4 + quad) ^ (row & 7)) << 3)];
            }
            #pragma unroll
            for (int ni = 0; ni < 4; ni++) {
                const int row = wsd * 64 + ni * 16 + l16;
                bf[ni] = *(const f16x8*)
                    &ts[row * 64 + (((kk * 4 + quad) ^ (row & 7)) << 3)];
            }
            #pragma unroll
            for (int mi = 0; mi < 4; mi++)
                #pragma unroll
                for (int ni = 0; ni < 4; ni++)
                    acc[mi][ni] = __builtin_amdgcn_mfma_f32_16x16x32_f16(
                        af[mi], bf[ni], acc[mi][ni], 0, 0, 0);
        }
    }

    const float scale = (p == 1) ? LOG2E : 1.0f;
    if (p < 2) {
        f16* yt = (p == 0) ? qt : kt;
        const float* bg = (p == 0) ? bq : bk;
        #pragma unroll
        for (int mi = 0; mi < 4; mi++) {
            const int o_in = half * 128 + wm * 64 + mi * 16 + quad * 4;
            const float4 b4 = *(const float4*)&bg[o_in];
            const int h = o_in >> 6;
            const int d = o_in & 63;
            #pragma unroll
            for (int ni = 0; ni < 4; ni++) {
                const int n = bx * 128 + wsd * 64 + ni * 16 + l16;
                f16x4 w;
                w.x = (f16)((acc[mi][ni][0] + b4.x) * scale);
                w.y = (f16)((acc[mi][ni][1] + b4.y) * scale);
                w.z = (f16)((acc[mi][ni][2] + b4.z) * scale);
                w.w = (f16)((acc[mi][ni][3] + b4.w) * scale);
                *(f16x4*)&yt[(((size_t)b * NH + h) * Nn + n) * Dh + d] = w;
            }
        }
    } else {
        #pragma unroll
        for (int ni = 0; ni < 4; ni++) {
            const int c  = half * 128 + wsd * 64 + ni * 16 + l16;
            const float bs = bv[c];
            #pragma unroll
            for (int mi = 0; mi < 4; mi++) {
                const int n = bx * 128 + wm * 64 + mi * 16 + quad * 4;
                f16x4 w;
                w.x = (f16)(acc[mi][ni][0] + bs);
                w.y = (f16)(acc[mi][ni][1] + bs);
                w.z = (f16)(acc[mi][ni][2] + bs);
                w.w = (f16)(acc[mi][ni][3] + bs);
                *(f16x4*)&vb[((size_t)b * Cch + c) * Nn + n] = w;
            }
        }
    }
}

// ---------------------------------------------------------------------------
// Flash attention. BI=64 (wave owns 16 q-rows), BJ=64. 1D grid with XCD
// swizzle: g = itile*64 + bh  ->  all 16 i-tiles of a (b,h) on one XCD.
// A-fragments (q|rel) loaded directly from global (j-invariant, no LDS).
// K/Q/V tiles staged via global_load_lds with source-XOR swizzle.
// Softmax in base-2 (k, rel pre-scaled by log2e). Row sums via MFMA ones.
// grid = 1024 blocks (64 bh-groups x 16 i-tiles).  // <-- round-6 bug: was 512
// ---------------------------------------------------------------------------
__global__ __launch_bounds__(256, 4) void attn_mfma(
    const f16* __restrict__ qt, const f16* __restrict__ kt,
    const f16* __restrict__ relt, const f16* __restrict__ vb,
    float* __restrict__ out)
{
    const int g  = blockIdx.x;
    const int bh = g & 63;
    const int i0 = (g >> 6) * 64;
    const int b  = bh >> 2;
    const int h  = bh & 3;

    const f16* qtb = qt  + (size_t)bh * Nn * Dh;            // [n][64]
    const f16* ktb = kt  + (size_t)bh * Nn * Dh;            // [n][64]
    const f16* rlt = relt + (size_t)h * Nn * Dh;            // [n][64]
    const f16* vbb = vb  + (size_t)(b * Cch + h * Dh) * Nn; // [d][1024]

    __shared__ f16 Ka_s[64 * 128];  // 16 KB  [j][128: k|q], swizzled
    __shared__ f16 v_s [64 * 64];   //  8 KB  [d][j], swizzled
    __shared__ f16 Pt_s[64 * 64];   //  8 KB  [i][j], swizzled

    const int t    = threadIdx.x;
    const int wave = t >> 6;
    const int lane = t & 63;
    const int l16  = lane & 15;
    const int quad = lane >> 4;

    // ---- j-invariant A-fragments straight from global ----
    const int arow = i0 + wave * 16 + l16;
    f16x8 af[4];
    af[0] = *(const f16x8*)&qtb[(size_t)arow * Dh + quad * 8];
    af[1] = *(const f16x8*)&qtb[(size_t)arow * Dh + 32 + quad * 8];
    af[2] = *(const f16x8*)&rlt[(size_t)arow * Dh + quad * 8];
    af[3] = *(const f16x8*)&rlt[(size_t)arow * Dh + 32 + quad * 8];

    f16x8 ones;
    #pragma unroll
    for (int u = 0; u < 8; u++) ones[u] = (f16)1.0f;

    f32x4 Of[4], Ol;
    Ol = (f32x4){0.f, 0.f, 0.f, 0.f};
    #pragma unroll
    for (int ds = 0; ds < 4; ds++) Of[ds] = (f32x4){0.f, 0.f, 0.f, 0.f};
    float m_r[4];
    #pragma unroll
    for (int r = 0; r < 4; r++) m_r[r] = -1e30f;

    for (int j0 = 0; j0 < Nn; j0 += 64) {
        __syncthreads();   // prior iter's LDS reads complete
        // Ka = [k | q] : 64 rows x 16 chunks, source-XOR swizzle
        #pragma unroll
        for (int rep = 0; rep < 4; rep++) {
            const int e   = t + rep * 256;
            const int row = e >> 4;
            const int c8s = (e & 15) ^ (row & 7);   // bit3 (k/q select) preserved
            const f16* src = (c8s < 8)
                ? &ktb[(size_t)(j0 + row) * Dh + c8s * 8]
                : &qtb[(size_t)(j0 + row) * Dh + (c8s - 8) * 8];
            gld16(src, &Ka_s[((size_t)rep * 256 + wave * 64) * 8]);
        }
        // V : 64 rows x 8 chunks
        #pragma unroll
        for (int rep = 0; rep < 2; rep++) {
            const int e   = t + rep * 256;
            const int row = e >> 3;
            const int c8s = (e & 7) ^ (row & 7);
            gld16(&vbb[(size_t)row * Nn + j0 + c8s * 8],
                  &v_s[((size_t)rep * 256 + wave * 64) * 8]);
        }
        __syncthreads();   // drains vmcnt

        // ---- S = Qa·Ka^T : 16 rows x 64 cols, K=128 ----
        f32x4 Sf[4];
        #pragma unroll
        for (int js = 0; js < 4; js++) Sf[js] = (f32x4){0.f, 0.f, 0.f, 0.f};
        #pragma unroll
        for (int k = 0; k < 4; k++) {
            f16x8 bb[4];
            #pragma unroll
            for (int js = 0; js < 4; js++) {
                const int row = js * 16 + l16;
                bb[js] = *(const f16x8*)
                    &Ka_s[row * 128 + (((k * 4 + quad) ^ (row & 7)) << 3)];
            }
            #pragma unroll
            for (int js = 0; js < 4; js++)
                Sf[js] = __builtin_amdgcn_mfma_f32_16x16x32_f16(
                    af[k], bb[js], Sf[js], 0, 0, 0);
        }

        // ---- online softmax (base-2) ----
        #pragma unroll
        for (int r = 0; r < 4; r++) {
            float tm = fmaxf(fmaxf(Sf[0][r], Sf[1][r]), fmaxf(Sf[2][r], Sf[3][r]));
            tm = fmaxf(tm, __shfl_xor(tm, 1));
            tm = fmaxf(tm, __shfl_xor(tm, 2));
            tm = fmaxf(tm, __shfl_xor(tm, 4));
            tm = fmaxf(tm, __shfl_xor(tm, 8));
            const float mnew  = fmaxf(m_r[r], tm);
            const float alpha = exp2f(m_r[r] - mnew);
            m_r[r] = mnew;

            const int row = wave * 16 + quad * 4 + r;
            const int rx  = row & 7;
            #pragma unroll
            for (int js = 0; js < 4; js++) {
                const float p = exp2f(Sf[js][r] - mnew);
                const int col = js * 16 + l16;
                Pt_s[row * 64 + (((col >> 3) ^ rx) << 3) + (col & 7)] = (f16)p;
            }
            #pragma unroll
            for (int ds = 0; ds < 4; ds++) Of[ds][r] *= alpha;
            Ol[r] *= alpha;
        }
        // Pt rows are wave-private: in-wave LDS ordering, no barrier

        // ---- O += P·V^T (K=64); l += P·1 ----
        #pragma unroll
        for (int ks = 0; ks < 2; ks++) {
            const int prow = wave * 16 + l16;
            f16x8 pa = *(const f16x8*)
                &Pt_s[prow * 64 + (((ks * 4 + quad) ^ (prow & 7)) << 3)];
            #pragma unroll
            for (int ds = 0; ds < 4; ds++) {
                const int vrow = ds * 16 + l16;
                f16x8 vv = *(const f16x8*)
                    &v_s[vrow * 64 + (((ks * 4 + quad) ^ (vrow & 7)) << 3)];
                Of[ds] = __builtin_amdgcn_mfma_f32_16x16x32_f16(
                    pa, vv, Of[ds], 0, 0, 0);
            }
            Ol = __builtin_amdgcn_mfma_f32_16x16x32_f16(pa, ones, Ol, 0, 0, 0);
        }
    }

    // ---- epilogue: out[b][h*64+d][i] = O/l ----
    #pragma unroll
    for (int r = 0; r < 4; r++) {
        const float inv = 1.0f / Ol[r];
        const int i = i0 + wave * 16 + quad * 4 + r;
        #pragma unroll
        for (int ds = 0; ds < 4; ds++) {
            const int d = ds * 16 + l16;
            out[((size_t)(b * Cch + h * Dh + d)) * Nn + i] = Of[ds][r] * inv;
        }
    }
}

// ---------------------------------------------------------------------------
extern "C" void kernel_launch(void* const* d_in, const int* in_sizes, int n_in,
                              void* d_out, int out_size, void* d_ws, size_t ws_size,
                              hipStream_t stream)
{
    const float* x     = (const float*)d_in[0];
    const float* Wq    = (const float*)d_in[1];
    const float* bq    = (const float*)d_in[2];
    const float* Wk    = (const float*)d_in[3];
    const float* bk    = (const float*)d_in[4];
    const float* Wv    = (const float*)d_in[5];
    const float* bv    = (const float*)d_in[6];
    const float* rel_h = (const float*)d_in[7];
    const float* rel_w = (const float*)d_in[8];

    f16* ws = (f16*)d_ws;
    const size_t SZQ = (size_t)Bb * NH * Nn * Dh;    // 4 Mi elems
    f16* qt   = ws;                                  // 8 MB
    f16* kt   = ws + SZQ;                            // 8 MB
    f16* vbuf = ws + 2 * SZQ;                        // 8 MB
    f16* relt = ws + 3 * SZQ;                        // 0.5 MB
    f16* xth  = ws + 3 * SZQ + (size_t)NH * Nn * Dh; // 8 MB  [b][n][c]
    f16* Wh   = xth + SZQ;                           // 0.4 MB [768][256]

    prep_kernel<<<dim3(2816), 256, 0, stream>>>(
        x, Wq, Wk, Wv, rel_h, rel_w, xth, Wh, relt);
    gemm_qkv<<<dim3(Nn / 128, 6, Bb), 256, 0, stream>>>(
        Wh, xth, bq, bk, bv, qt, kt, vbuf);
    attn_mfma<<<dim3(64 * (Nn / 64)), 256, 0, stream>>>(   // 1024 blocks, 1D
        qt, kt, relt, vbuf, (float*)d_out);
}

// Round 8
// 160.546 us; speedup vs baseline: 1.0051x; 1.0051x over previous
//
#include <hip/hip_runtime.h>

// B=16, C=256, HEADS=4, d=64, N=W*H=1024
constexpr int Bb  = 16;
constexpr int Cch = 256;
constexpr int NH  = 4;
constexpr int Dh  = 64;
constexpr int Nn  = 1024;

typedef _Float16 f16;
typedef __attribute__((ext_vector_type(8))) _Float16 f16x8;
typedef __attribute__((ext_vector_type(4))) _Float16 f16x4;
typedef __attribute__((ext_vector_type(4))) float    f32x4;

#define LOG2E 1.44269504088896f

// async 16B global->LDS. lds base must be wave-uniform; HW adds lane*16.
__device__ inline void gld16(const f16* g, const f16* lds_wave_base) {
    __builtin_amdgcn_global_load_lds(
        (const __attribute__((address_space(1))) unsigned int*)g,
        (__attribute__((address_space(3))) unsigned int*)lds_wave_base,
        16, 0, 0);
}

// ---------------------------------------------------------------------------
// Fused prep: xtrans (blocks 0..1023) | relt (1024..2047) | wcast (2048..2815)
// rel is pre-scaled by log2e (softmax via exp2).
// ---------------------------------------------------------------------------
__global__ __launch_bounds__(256) void prep_kernel(
    const float* __restrict__ x,
    const float* __restrict__ Wq, const float* __restrict__ Wk,
    const float* __restrict__ Wv,
    const float* __restrict__ rel_h, const float* __restrict__ rel_w,
    f16* __restrict__ xt, f16* __restrict__ Wh, f16* __restrict__ rel_t)
{
    const int gx = blockIdx.x;
    const int t  = threadIdx.x;
    __shared__ float T[64][65];

    if (gx < 1024) {
        const int n0 = (gx & 15) * 64;
        const int c0 = ((gx >> 4) & 3) * 64;
        const int b  = gx >> 6;
        #pragma unroll
        for (int rep = 0; rep < 16; rep++) {
            const int e  = t + rep * 256;
            const int r  = e >> 6;
            const int cc = e & 63;
            T[r][cc] = x[((size_t)b * Cch + c0 + r) * Nn + n0 + cc];
        }
        __syncthreads();
        #pragma unroll
        for (int rep = 0; rep < 4; rep++) {
            const int e  = t + rep * 256;
            const int nn = e >> 4;
            const int c4 = e & 15;
            f16x4 w;
            w.x = (f16)T[c4 * 4 + 0][nn];
            w.y = (f16)T[c4 * 4 + 1][nn];
            w.z = (f16)T[c4 * 4 + 2][nn];
            w.w = (f16)T[c4 * 4 + 3][nn];
            *(f16x4*)&xt[((size_t)b * Nn + n0 + nn) * Cch + c0 + c4 * 4] = w;
        }
    } else if (gx < 2048) {
        const int idx = (gx - 1024) * 256 + t;     // NH*Nn*Dh = 262144
        const int d = idx & 63;
        const int n = (idx >> 6) & (Nn - 1);
        const int h = idx >> 16;
        const int hd = h * 64 + d;
        rel_t[idx] = (f16)((rel_h[hd * 32 + (n & 31)] + rel_w[hd * 32 + (n >> 5)])
                           * LOG2E);
    } else {
        const int idx = (gx - 2048) * 256 + t;     // 768*256
        const int og  = idx >> 8;
        const int c   = idx & 255;
        const int p   = og >> 8;
        const int o   = og & 255;
        const float* W = (p == 0) ? Wq : (p == 1) ? Wk : Wv;
        Wh[idx] = (f16)W[o * 256 + c];
    }
}

// ---------------------------------------------------------------------------
// QKV projection GEMM, fp16 MFMA, BK=64, global_load_lds + source-XOR swizzle.
// k output pre-scaled by log2e. (unchanged from round 7)
// ---------------------------------------------------------------------------
__global__ __launch_bounds__(256, 3) void gemm_qkv(
    const f16* __restrict__ Wh, const f16* __restrict__ xt,
    const float* __restrict__ bq, const float* __restrict__ bk,
    const float* __restrict__ bv,
    f16* __restrict__ qt, f16* __restrict__ kt, f16* __restrict__ vb)
{
    const int bx   = blockIdx.x;
    const int y    = blockIdx.y;
    const int b    = blockIdx.z;
    const int p    = y >> 1;
    const int half = y & 1;

    __shared__ f16 Wt[128 * 64];   // 16 KB
    __shared__ f16 Xt[128 * 64];   // 16 KB

    const int t    = threadIdx.x;
    const int wave = t >> 6;
    const int lane = t & 63;
    const int l16  = lane & 15;
    const int quad = lane >> 4;
    const int wm   = wave >> 1;
    const int wsd  = wave & 1;

    f32x4 acc[4][4];
    #pragma unroll
    for (int mi = 0; mi < 4; mi++)
        #pragma unroll
        for (int ni = 0; ni < 4; ni++) acc[mi][ni] = (f32x4){0.f, 0.f, 0.f, 0.f};

    const f16* Wg = Wh + (size_t)y * 128 * 256;
    const f16* Xg = xt + ((size_t)b * Nn + bx * 128) * 256;

    for (int c0 = 0; c0 < 256; c0 += 64) {
        __syncthreads();
        #pragma unroll
        for (int rep = 0; rep < 4; rep++) {
            const int e   = t + rep * 256;
            const int row = e >> 3;
            const int c8s = (e & 7) ^ (row & 7);
            gld16(&Wg[(size_t)row * 256 + c0 + c8s * 8],
                  &Wt[((size_t)rep * 256 + wave * 64) * 8]);
        }
        #pragma unroll
        for (int rep = 0; rep < 4; rep++) {
            const int e   = t + rep * 256;
            const int row = e >> 3;
            const int c8s = (e & 7) ^ (row & 7);
            gld16(&Xg[(size_t)row * 256 + c0 + c8s * 8],
                  &Xt[((size_t)rep * 256 + wave * 64) * 8]);
        }
        __syncthreads();

        const f16* tf = (p < 2) ? Wt : Xt;
        const f16* ts = (p < 2) ? Xt : Wt;
        #pragma unroll
        for (int kk = 0; kk < 2; kk++) {
            f16x8 af[4], bf[4];
            #pragma unroll
            for (int mi = 0; mi < 4; mi++) {
                const int row = wm * 64 + mi * 16 + l16;
                af[mi] = *(const f16x8*)
                    &tf[row * 64 + (((kk * 4 + quad) ^ (row & 7)) << 3)];
            }
            #pragma unroll
            for (int ni = 0; ni < 4; ni++) {
                const int row = wsd * 64 + ni * 16 + l16;
                bf[ni] = *(const f16x8*)
                    &ts[row * 64 + (((kk * 4 + quad) ^ (row & 7)) << 3)];
            }
            #pragma unroll
            for (int mi = 0; mi < 4; mi++)
                #pragma unroll
                for (int ni = 0; ni < 4; ni++)
                    acc[mi][ni] = __builtin_amdgcn_mfma_f32_16x16x32_f16(
                        af[mi], bf[ni], acc[mi][ni], 0, 0, 0);
        }
    }

    const float scale = (p == 1) ? LOG2E : 1.0f;
    if (p < 2) {
        f16* yt = (p == 0) ? qt : kt;
        const float* bg = (p == 0) ? bq : bk;
        #pragma unroll
        for (int mi = 0; mi < 4; mi++) {
            const int o_in = half * 128 + wm * 64 + mi * 16 + quad * 4;
            const float4 b4 = *(const float4*)&bg[o_in];
            const int h = o_in >> 6;
            const int d = o_in & 63;
            #pragma unroll
            for (int ni = 0; ni < 4; ni++) {
                const int n = bx * 128 + wsd * 64 + ni * 16 + l16;
                f16x4 w;
                w.x = (f16)((acc[mi][ni][0] + b4.x) * scale);
                w.y = (f16)((acc[mi][ni][1] + b4.y) * scale);
                w.z = (f16)((acc[mi][ni][2] + b4.z) * scale);
                w.w = (f16)((acc[mi][ni][3] + b4.w) * scale);
                *(f16x4*)&yt[(((size_t)b * NH + h) * Nn + n) * Dh + d] = w;
            }
        }
    } else {
        #pragma unroll
        for (int ni = 0; ni < 4; ni++) {
            const int c  = half * 128 + wsd * 64 + ni * 16 + l16;
            const float bs = bv[c];
            #pragma unroll
            for (int mi = 0; mi < 4; mi++) {
                const int n = bx * 128 + wm * 64 + mi * 16 + quad * 4;
                f16x4 w;
                w.x = (f16)(acc[mi][ni][0] + bs);
                w.y = (f16)(acc[mi][ni][1] + bs);
                w.z = (f16)(acc[mi][ni][2] + bs);
                w.w = (f16)(acc[mi][ni][3] + bs);
                *(f16x4*)&vb[((size_t)b * Cch + c) * Nn + n] = w;
            }
        }
    }
}

// ---------------------------------------------------------------------------
// Flash attention. BI=128 (each wave owns 32 q-rows, ms=2 so B-fragments are
// amortized over 2x MFMAs), BJ=64. 1D grid of 512 blocks, XCD-local:
// g = itile*64 + bh -> g%8 = bh%8, all 8 i-tiles of a (b,h) on one XCD.
// A-fragments (q|rel) in registers from global (j-invariant). K/Q/V staged
// via global_load_lds + source-XOR swizzle. Base-2 softmax. l via MFMA ones.
// LDS = 16+8+16 = 40 KB.
// ---------------------------------------------------------------------------
__global__ __launch_bounds__(256, 2) void attn_mfma(
    const f16* __restrict__ qt, const f16* __restrict__ kt,
    const f16* __restrict__ relt, const f16* __restrict__ vb,
    float* __restrict__ out)
{
    const int g  = blockIdx.x;          // 512 blocks
    const int bh = g & 63;
    const int i0 = (g >> 6) * 128;
    const int b  = bh >> 2;
    const int h  = bh & 3;

    const f16* qtb = qt  + (size_t)bh * Nn * Dh;            // [n][64]
    const f16* ktb = kt  + (size_t)bh * Nn * Dh;            // [n][64]
    const f16* rlt = relt + (size_t)h * Nn * Dh;            // [n][64]
    const f16* vbb = vb  + (size_t)(b * Cch + h * Dh) * Nn; // [d][1024]

    __shared__ f16 Ka_s[64 * 128];  // 16 KB  [j][128: k|q], swizzled
    __shared__ f16 v_s [64 * 64];   //  8 KB  [d][j], swizzled
    __shared__ f16 Pt_s[128 * 64];  // 16 KB  [i][j], swizzled

    const int t    = threadIdx.x;
    const int wave = t >> 6;
    const int lane = t & 63;
    const int l16  = lane & 15;
    const int quad = lane >> 4;

    // ---- j-invariant A-fragments straight from global: 2 m-subtiles ----
    f16x8 af[2][4];
    #pragma unroll
    for (int ms = 0; ms < 2; ms++) {
        const int arow = i0 + wave * 32 + ms * 16 + l16;
        af[ms][0] = *(const f16x8*)&qtb[(size_t)arow * Dh + quad * 8];
        af[ms][1] = *(const f16x8*)&qtb[(size_t)arow * Dh + 32 + quad * 8];
        af[ms][2] = *(const f16x8*)&rlt[(size_t)arow * Dh + quad * 8];
        af[ms][3] = *(const f16x8*)&rlt[(size_t)arow * Dh + 32 + quad * 8];
    }

    f16x8 ones;
    #pragma unroll
    for (int u = 0; u < 8; u++) ones[u] = (f16)1.0f;

    f32x4 Of[2][4], Ol[2];
    float m_r[2][4];
    #pragma unroll
    for (int ms = 0; ms < 2; ms++) {
        Ol[ms] = (f32x4){0.f, 0.f, 0.f, 0.f};
        #pragma unroll
        for (int ds = 0; ds < 4; ds++) Of[ms][ds] = (f32x4){0.f, 0.f, 0.f, 0.f};
        #pragma unroll
        for (int r = 0; r < 4; r++) m_r[ms][r] = -1e30f;
    }

    for (int j0 = 0; j0 < Nn; j0 += 64) {
        __syncthreads();   // prior iter's LDS reads complete
        // Ka = [k | q] : 64 rows x 16 chunks, source-XOR swizzle
        #pragma unroll
        for (int rep = 0; rep < 4; rep++) {
            const int e   = t + rep * 256;
            const int row = e >> 4;
            const int c8s = (e & 15) ^ (row & 7);   // bit3 (k/q select) preserved
            const f16* src = (c8s < 8)
                ? &ktb[(size_t)(j0 + row) * Dh + c8s * 8]
                : &qtb[(size_t)(j0 + row) * Dh + (c8s - 8) * 8];
            gld16(src, &Ka_s[((size_t)rep * 256 + wave * 64) * 8]);
        }
        // V : 64 rows x 8 chunks
        #pragma unroll
        for (int rep = 0; rep < 2; rep++) {
            const int e   = t + rep * 256;
            const int row = e >> 3;
            const int c8s = (e & 7) ^ (row & 7);
            gld16(&vbb[(size_t)row * Nn + j0 + c8s * 8],
                  &v_s[((size_t)rep * 256 + wave * 64) * 8]);
        }
        __syncthreads();   // drains vmcnt

        // ---- S = Qa·Ka^T : 2x16 rows x 64 cols, K=128 ----
        f32x4 Sf[2][4];
        #pragma unroll
        for (int ms = 0; ms < 2; ms++)
            #pragma unroll
            for (int js = 0; js < 4; js++) Sf[ms][js] = (f32x4){0.f, 0.f, 0.f, 0.f};
        #pragma unroll
        for (int k = 0; k < 4; k++) {
            f16x8 bb[4];
            #pragma unroll
            for (int js = 0; js < 4; js++) {
                const int row = js * 16 + l16;
                bb[js] = *(const f16x8*)
                    &Ka_s[row * 128 + (((k * 4 + quad) ^ (row & 7)) << 3)];
            }
            #pragma unroll
            for (int ms = 0; ms < 2; ms++)
                #pragma unroll
                for (int js = 0; js < 4; js++)
                    Sf[ms][js] = __builtin_amdgcn_mfma_f32_16x16x32_f16(
                        af[ms][k], bb[js], Sf[ms][js], 0, 0, 0);
        }

        // ---- online softmax (base-2) ----
        #pragma unroll
        for (int ms = 0; ms < 2; ms++) {
            #pragma unroll
            for (int r = 0; r < 4; r++) {
                float tm = fmaxf(fmaxf(Sf[ms][0][r], Sf[ms][1][r]),
                                 fmaxf(Sf[ms][2][r], Sf[ms][3][r]));
                tm = fmaxf(tm, __shfl_xor(tm, 1));
                tm = fmaxf(tm, __shfl_xor(tm, 2));
                tm = fmaxf(tm, __shfl_xor(tm, 4));
                tm = fmaxf(tm, __shfl_xor(tm, 8));
                const float mnew  = fmaxf(m_r[ms][r], tm);
                const float alpha = exp2f(m_r[ms][r] - mnew);
                m_r[ms][r] = mnew;

                const int row = wave * 32 + ms * 16 + quad * 4 + r;
                const int rx  = row & 7;
                #pragma unroll
                for (int js = 0; js < 4; js++) {
                    const float p = exp2f(Sf[ms][js][r] - mnew);
                    const int col = js * 16 + l16;
                    Pt_s[row * 64 + (((col >> 3) ^ rx) << 3) + (col & 7)] = (f16)p;
                }
                #pragma unroll
                for (int ds = 0; ds < 4; ds++) Of[ms][ds][r] *= alpha;
                Ol[ms][r] *= alpha;
            }
        }
        // Pt rows are wave-private: in-wave LDS ordering, no barrier

        // ---- O += P·V^T (K=64); l += P·1 ----
        #pragma unroll
        for (int ks = 0; ks < 2; ks++) {
            f16x8 vv[4];
            #pragma unroll
            for (int ds = 0; ds < 4; ds++) {
                const int vrow = ds * 16 + l16;
                vv[ds] = *(const f16x8*)
                    &v_s[vrow * 64 + (((ks * 4 + quad) ^ (vrow & 7)) << 3)];
            }
            #pragma unroll
            for (int ms = 0; ms < 2; ms++) {
                const int prow = wave * 32 + ms * 16 + l16;
                f16x8 pa = *(const f16x8*)
                    &Pt_s[prow * 64 + (((ks * 4 + quad) ^ (prow & 7)) << 3)];
                #pragma unroll
                for (int ds = 0; ds < 4; ds++)
                    Of[ms][ds] = __builtin_amdgcn_mfma_f32_16x16x32_f16(
                        pa, vv[ds], Of[ms][ds], 0, 0, 0);
                Ol[ms] = __builtin_amdgcn_mfma_f32_16x16x32_f16(
                    pa, ones, Ol[ms], 0, 0, 0);
            }
        }
    }

    // ---- epilogue: out[b][h*64+d][i] = O/l ----
    #pragma unroll
    for (int ms = 0; ms < 2; ms++) {
        #pragma unroll
        for (int r = 0; r < 4; r++) {
            const float inv = 1.0f / Ol[ms][r];
            const int i = i0 + wave * 32 + ms * 16 + quad * 4 + r;
            #pragma unroll
            for (int ds = 0; ds < 4; ds++) {
                const int d = ds * 16 + l16;
                out[((size_t)(b * Cch + h * Dh + d)) * Nn + i] = Of[ms][ds][r] * inv;
            }
        }
    }
}

// ---------------------------------------------------------------------------
extern "C" void kernel_launch(void* const* d_in, const int* in_sizes, int n_in,
                              void* d_out, int out_size, void* d_ws, size_t ws_size,
                              hipStream_t stream)
{
    const float* x     = (const float*)d_in[0];
    const float* Wq    = (const float*)d_in[1];
    const float* bq    = (const float*)d_in[2];
    const float* Wk    = (const float*)d_in[3];
    const float* bk    = (const float*)d_in[4];
    const float* Wv    = (const float*)d_in[5];
    const float* bv    = (const float*)d_in[6];
    const float* rel_h = (const float*)d_in[7];
    const float* rel_w = (const float*)d_in[8];

    f16* ws = (f16*)d_ws;
    const size_t SZQ = (size_t)Bb * NH * Nn * Dh;    // 4 Mi elems
    f16* qt   = ws;                                  // 8 MB
    f16* kt   = ws + SZQ;                            // 8 MB
    f16* vbuf = ws + 2 * SZQ;                        // 8 MB
    f16* relt = ws + 3 * SZQ;                        // 0.5 MB
    f16* xth  = ws + 3 * SZQ + (size_t)NH * Nn * Dh; // 8 MB  [b][n][c]
    f16* Wh   = xth + SZQ;                           // 0.4 MB [768][256]

    prep_kernel<<<dim3(2816), 256, 0, stream>>>(
        x, Wq, Wk, Wv, rel_h, rel_w, xth, Wh, relt);
    gemm_qkv<<<dim3(Nn / 128, 6, Bb), 256, 0, stream>>>(
        Wh, xth, bq, bk, bv, qt, kt, vbuf);
    attn_mfma<<<dim3(64 * (Nn / 128)), 256, 0, stream>>>(   // 512 blocks, 1D
        qt, kt, relt, vbuf, (float*)d_out);
}